// Round 16
// baseline (207.395 us; speedup 1.0000x reference)
//
#include <hip/hip_runtime.h>
#include <stdint.h>

#define B_N 16384
#define H_N 256
#define IN_W 258
#define GX_N 70
#define GY_N 70
#define SW_N 2
#define KK_N 25

typedef __bf16 bf16x8 __attribute__((ext_vector_type(8)));
typedef __bf16 bf16x4 __attribute__((ext_vector_type(4)));
typedef __bf16 bf16x2 __attribute__((ext_vector_type(2)));
typedef float f32x8 __attribute__((ext_vector_type(8)));
typedef float f32x4 __attribute__((ext_vector_type(4)));
typedef float f32x2 __attribute__((ext_vector_type(2)));

#define AS1 __attribute__((address_space(1)))
#define AS3 __attribute__((address_space(3)))

static __device__ __forceinline__ void gload16(const void* g, void* l) {
    __builtin_amdgcn_global_load_lds((const AS1 uint32_t*)g, (AS3 uint32_t*)l, 16, 0, 0);
}

// ---- ws layout (bf16 elements) ----
// AB    at 0        : UNUSED now (A staged straight from f32 inputs)
// wfull at 8388608  : [1024][512]   rows j=c*256+col, c in {r,i,s,n};
//                     k<256 -> wih[base_c+col][k], k>=256 -> whh[base_c+col][k-256]
//                     base_c = {0,256,768,512}
// woutB at 8912896  : [256][512]
// comb  at 9043968  : [16384][512]  ([mix|q])               16 MB
// ugsg  at 17432576 : [16384][256][2] (ug,sg interleaved)   16 MB
#define E_AB   8388608ULL
#define E_WF   8912896ULL
#define E_WOUT 9043968ULL
#define E_COMB 9043968ULL
#define E_UGSG 17432576ULL

// Weights-only cast (AB section fused into gates staging — saves ~49MB
// HBM traffic + a 16MB sweep). 655K elements -> grid 320.
__global__ __launch_bounds__(256) void cast_kernel(
    const float* __restrict__ wih, const float* __restrict__ whh,
    const float* __restrict__ wout, __bf16* __restrict__ dst)
{
    size_t g = (size_t)blockIdx.x * blockDim.x + threadIdx.x;
    size_t stride = (size_t)gridDim.x * blockDim.x;
    for (size_t e = E_AB + g * 8; e < E_WOUT; e += stride * 8) {
        const float* src;
        if (e < E_WF) {
            size_t off = e - E_AB;
            size_t j = off >> 9;       // 0..1023
            size_t k = off & 511;
            size_t c = j >> 8;         // 0..3
            size_t col = j & 255;
            size_t base = (c == 0) ? 0 : (c == 1) ? 256 : (c == 2) ? 768 : 512;
            const float* srcm = (k < 256) ? wih : whh;
            src = srcm + (base + col) * 256 + (k & 255);
        } else {
            src = wout + (e - E_WF);
        }
        const f32x4* s4 = reinterpret_cast<const f32x4*>(src);
        f32x4 a = s4[0], b = s4[1];
        bf16x8 o;
        o[0] = (__bf16)a.x; o[1] = (__bf16)a.y; o[2] = (__bf16)a.z; o[3] = (__bf16)a.w;
        o[4] = (__bf16)b.x; o[5] = (__bf16)b.y; o[6] = (__bf16)b.z; o[7] = (__bf16)b.w;
        *reinterpret_cast<bf16x8*>(dst + e) = o;
    }
}

// A-operand direct-from-f32 loader: 8 consecutive k from feat (in_t row,
// stride 258 -> only 8B-aligned: f32x2 loads) or hid (16B-aligned: f32x4).
// Branch is wave-uniform (k0 depends on sA = per-wave constant + kt).
static __device__ __forceinline__ f32x8 loadA8(
    const float* __restrict__ featp, const float* __restrict__ hidp, int k0)
{
    f32x8 r;
    if (k0 < 256) {
        const f32x2* p = reinterpret_cast<const f32x2*>(featp + k0);
        f32x2 a = p[0], b = p[1], c = p[2], d = p[3];
        r[0] = a.x; r[1] = a.y; r[2] = b.x; r[3] = b.y;
        r[4] = c.x; r[5] = c.y; r[6] = d.x; r[7] = d.y;
    } else {
        const f32x4* p = reinterpret_cast<const f32x4*>(hidp + (k0 - 256));
        f32x4 a = p[0], b = p[1];
        r[0] = a.x; r[1] = a.y; r[2] = a.z; r[3] = a.w;
        r[4] = b.x; r[5] = b.y; r[6] = b.z; r[7] = b.w;
    }
    return r;
}
static __device__ __forceinline__ void cvtStore(__bf16* dst, f32x8 v) {
    bf16x8 o;
#pragma unroll
    for (int q = 0; q < 8; q++) o[q] = (__bf16)v[q];
    *reinterpret_cast<bf16x8*>(dst) = o;
}

// Fused gates GEMM, K=512 concat form. r6-proven 2-phase dbuf pipeline,
// with A staged DIRECTLY from f32 inputs (reg-stage: load f32 early,
// cvt+ds_write late — T14 split so HBM latency hides under the MFMAs).
// B still via global_load_lds (wfull bf16, L2-resident).
// block = 128 rows x 128 cols, 4 waves, wave 32x128, acc 80 regs.
// LDS 32KB -> 4 blocks/CU (grid 1024 = 4/CU).
__global__ __launch_bounds__(256, 2) void gates_gemm(
    const float* __restrict__ in_t, const float* __restrict__ hid,
    const __bf16* __restrict__ wfull,
    const float* __restrict__ b_ih, const float* __restrict__ b_hh,
    __bf16* __restrict__ comb, __bf16* __restrict__ ugsg)
{
    __shared__ __bf16 ldsA[2][4096];   // [buf][seg(4)][row(128)][8]
    __shared__ __bf16 ldsB[2][4096];   // [buf][seg(4)][brow(128)][8]
    const int t = threadIdx.x;
    const int lane = t & 63, w = t >> 6;
    const int lr = lane & 15, seg = lane >> 4;
    const int rb = blockIdx.x * 128;
    const int h0 = blockIdx.y * 32;

    // staging: thread t owns row (t&127), k-segs {sA, sA+2}, sA = t>>7
    const int rA = t & 127;
    const int sA = t >> 7;             // 0..1 (wave-uniform)
    const float* featp = in_t + (size_t)(rb + rA) * IN_W;
    const float* hidp  = hid + (size_t)(rb + rA) * 256;
    const int bc = rA >> 5, bcol = rA & 31;  // brow -> wfull row bc*256+h0+bcol
    const __bf16* gBt = wfull + (size_t)(bc * 256 + h0 + bcol) * 512 + sA * 8;
    __bf16* lA0 = &ldsA[0][t * 8];
    __bf16* lA1 = &ldsA[1][t * 8];
    __bf16* lB0 = &ldsB[0][t * 8];
    __bf16* lB1 = &ldsB[1][t * 8];

    f32x4 acc[2][6], accni[2][2], accnh[2][2];
#pragma unroll
    for (int rh = 0; rh < 2; rh++) {
#pragma unroll
        for (int cn = 0; cn < 6; cn++) acc[rh][cn] = (f32x4){0.f, 0.f, 0.f, 0.f};
        accni[rh][0] = (f32x4){0.f, 0.f, 0.f, 0.f};
        accni[rh][1] = (f32x4){0.f, 0.f, 0.f, 0.f};
        accnh[rh][0] = (f32x4){0.f, 0.f, 0.f, 0.f};
        accnh[rh][1] = (f32x4){0.f, 0.f, 0.f, 0.f};
    }

    // prologue: stage tile 0 into buf 0 (B async, A reg-staged)
    gload16(gBt + 0, lB0);
    gload16(gBt + 16, lB0 + 2048);
    {
        f32x8 a0 = loadA8(featp, hidp, sA * 8);
        f32x8 a1 = loadA8(featp, hidp, sA * 8 + 16);
        cvtStore(lA0, a0);
        cvtStore(lA0 + 2048, a1);
    }
    __syncthreads();   // vmcnt(0)+lgkmcnt(0): tile 0 complete

#pragma unroll 1
    for (int tt = 0; tt < 16; tt++) {
        const int cur = tt & 1;
        f32x8 a0, a1;
        if (tt < 15) {   // issue next tile: B fire-and-forget, A loads early
            const int kn = (tt + 1) * 32;
            __bf16* lb = cur ? lB0 : lB1;
            gload16(gBt + kn, lb);
            gload16(gBt + kn + 16, lb + 2048);
            a0 = loadA8(featp, hidp, kn + sA * 8);
            a1 = loadA8(featp, hidp, kn + sA * 8 + 16);
        }
        const __bf16* cA = ldsA[cur];
        const __bf16* cB = ldsB[cur];
        bf16x8 af[2];
#pragma unroll
        for (int rh = 0; rh < 2; rh++)
            af[rh] = *reinterpret_cast<const bf16x8*>(cA + seg * 1024 + (w * 32 + rh * 16 + lr) * 8);
#pragma unroll
        for (int cn = 0; cn < 6; cn++) {
            const int c = cn >> 1, hh = cn & 1;
            bf16x8 bb = *reinterpret_cast<const bf16x8*>(cB + seg * 1024 + (c * 32 + hh * 16 + lr) * 8);
#pragma unroll
            for (int rh = 0; rh < 2; rh++)
                acc[rh][(c << 1) + hh] = __builtin_amdgcn_mfma_f32_16x16x32_bf16(af[rh], bb, acc[rh][(c << 1) + hh], 0, 0, 0);
        }
        bf16x8 b6 = *reinterpret_cast<const bf16x8*>(cB + seg * 1024 + (96 + lr) * 8);
        bf16x8 b7 = *reinterpret_cast<const bf16x8*>(cB + seg * 1024 + (112 + lr) * 8);
        if (tt < 8) {
#pragma unroll
            for (int rh = 0; rh < 2; rh++) {
                accni[rh][0] = __builtin_amdgcn_mfma_f32_16x16x32_bf16(af[rh], b6, accni[rh][0], 0, 0, 0);
                accni[rh][1] = __builtin_amdgcn_mfma_f32_16x16x32_bf16(af[rh], b7, accni[rh][1], 0, 0, 0);
            }
        } else {
#pragma unroll
            for (int rh = 0; rh < 2; rh++) {
                accnh[rh][0] = __builtin_amdgcn_mfma_f32_16x16x32_bf16(af[rh], b6, accnh[rh][0], 0, 0, 0);
                accnh[rh][1] = __builtin_amdgcn_mfma_f32_16x16x32_bf16(af[rh], b7, accnh[rh][1], 0, 0, 0);
            }
        }
        if (tt < 15) {   // write-late: cvt + ds_write after compute
            __bf16* la = cur ? lA0 : lA1;
            cvtStore(la, a0);
            cvtStore(la + 2048, a1);
        }
        __syncthreads();   // vmcnt(0)+lgkm(0): next tile landed
    }

#pragma unroll
    for (int hh = 0; hh < 2; hh++) {
        const int col = h0 + hh * 16 + lr;
        const float br_ = b_ih[col] + b_hh[col];
        const float bi_ = b_ih[col + 256] + b_hh[col + 256];
        const float bs_ = b_ih[col + 768] + b_hh[col + 768];
        const float bni = b_ih[col + 512];
        const float bnh = b_hh[col + 512];
#pragma unroll
        for (int rh = 0; rh < 2; rh++) {
#pragma unroll
            for (int r = 0; r < 4; r++) {
                const int row = rb + w * 32 + rh * 16 + seg * 4 + r;
                float sr = acc[rh][hh][r] + br_;
                float si = acc[rh][2 + hh][r] + bi_;
                float ss = acc[rh][4 + hh][r] + bs_;
                float vni = accni[rh][hh][r] + bni;
                float vnh = accnh[rh][hh][r] + bnh;
                float rg = 1.f / (1.f + __expf(-sr));
                float ug = 1.f / (1.f + __expf(-si));
                float sg = 1.f / (1.f + __expf(-ss));
                float ng = tanhf(vni + rg * vnh);
                comb[(size_t)row * 512 + 256 + col] = (__bf16)ng;
                bf16x2 us;
                us.x = (__bf16)ug;
                us.y = (__bf16)sg;
                *reinterpret_cast<bf16x2*>(ugsg + ((size_t)row * 256 + col) * 2) = us;
            }
        }
    }
}

// DPP 64-lane sum (6 VALU adds, zero DS-pipe ops). CTRL is a template
// param. bound_ctrl=true: invalid source lane reads 0 (sum identity).
template <int CTRL>
static __device__ __forceinline__ float dpp_add_step(float x) {
    int xi = __builtin_bit_cast(int, x);
    int sh = __builtin_amdgcn_update_dpp(0, xi, CTRL, 0xf, 0xf, true);
    return x + __builtin_bit_cast(float, sh);
}
static __device__ __forceinline__ float wave_sum_readlane(float x) {
    x = dpp_add_step<0x111>(x);  // row_shr:1
    x = dpp_add_step<0x112>(x);  // row_shr:2
    x = dpp_add_step<0x114>(x);  // row_shr:4
    x = dpp_add_step<0x118>(x);  // row_shr:8
    x = dpp_add_step<0x142>(x);  // row_bcast:15
    x = dpp_add_step<0x143>(x);  // row_bcast:31 -> lane63 = total
    int s = __builtin_amdgcn_readlane(__builtin_bit_cast(int, x), 63);
    return __builtin_bit_cast(float, s);
}

// Attention v3 (r11-proven, 31.8us): wave per row, coalesced f32x4
// context loads held in registers (v[25], static-indexed), DPP-VALU
// reduction (no DS pipe), redundant per-lane softmax. No LDS.
__global__ __launch_bounds__(256) void attn_kernel(
    const float* __restrict__ in_t, const float* __restrict__ memory,
    __bf16* __restrict__ comb)
{
    const int w = threadIdx.x >> 6;
    const int lane = threadIdx.x & 63;
    const int b = blockIdx.x * 4 + w;
    const float* row_in = in_t + (size_t)b * IN_W;
    int gx = (int)row_in[256] + SW_N;
    int gy = (int)row_in[257] + SW_N;
    gx = min(max(gx, 0), GX_N - 1);
    gy = min(max(gy, 0), GY_N - 1);

    int xs[5], ys[5];
#pragma unroll
    for (int d = 0; d < 5; d++) {
        xs[d] = min(max(gx + d - SW_N, 0), GX_N - 1);
        ys[d] = min(max(gy + d - SW_N, 0), GY_N - 1);
    }

    bf16x4 qb = *reinterpret_cast<const bf16x4*>(comb + (size_t)b * 512 + 256 + lane * 4);
    const float q0 = (float)qb.x, q1 = (float)qb.y, q2 = (float)qb.z, q3 = (float)qb.w;

    f32x4 v[KK_N];
    float sc[KK_N];
#pragma unroll
    for (int k = 0; k < KK_N; k++) {       // full unroll: v[],sc[] static-indexed
        const int i = k / 5, j = k % 5;    // compile-time
        const f32x4* cp = reinterpret_cast<const f32x4*>(
            memory + ((size_t)xs[i] * GY_N + ys[j]) * H_N);
        v[k] = cp[lane];                   // coalesced 1KB/wave
        float p = q0 * v[k].x + q1 * v[k].y + q2 * v[k].z + q3 * v[k].w;
        sc[k] = wave_sum_readlane(p);      // 6 VALU-DPP + readlane, no DS
    }

    // softmax over 25 uniform scores (ref: attn==0 -> -inf mask; all-masked -> 0)
#pragma unroll
    for (int k = 0; k < KK_N; k++) sc[k] = (sc[k] == 0.f) ? -INFINITY : sc[k];
    float mx = -INFINITY;
#pragma unroll
    for (int k = 0; k < KK_N; k++) mx = fmaxf(mx, sc[k]);
    float d = 0.f;
    if (mx > -INFINITY) {
#pragma unroll
        for (int k = 0; k < KK_N; k++) { sc[k] = __expf(sc[k] - mx); d += sc[k]; }
    } else {
#pragma unroll
        for (int k = 0; k < KK_N; k++) sc[k] = 0.f;
    }
    const float inv = (d != 0.f) ? 1.f / d : 0.f;

    f32x4 o = (f32x4){0.f, 0.f, 0.f, 0.f};
#pragma unroll
    for (int k = 0; k < KK_N; k++) {
        const float wk = sc[k] * inv;
        o.x += wk * v[k].x; o.y += wk * v[k].y; o.z += wk * v[k].z; o.w += wk * v[k].w;
    }
    bf16x4 ob;
    ob.x = (__bf16)o.x; ob.y = (__bf16)o.y; ob.z = (__bf16)o.z; ob.w = (__bf16)o.w;
    *reinterpret_cast<bf16x4*>(comb + (size_t)b * 512 + lane * 4) = ob;
}

// Output GEMM (K=512) + tanh + final blend. r15 BK=64 version (8 K-steps,
// proven -3us): tile 64x64, 2-phase dbuf, LDS [buf][kb(2)][seg(4)][row(64)][8]
// = 32KB -> 4 blocks/CU at (256,4).
__global__ __launch_bounds__(256, 4) void out_gemm(
    const __bf16* __restrict__ comb, const __bf16* __restrict__ woB,
    const float* __restrict__ b_out, const __bf16* __restrict__ ugsg,
    const float* __restrict__ hidden, float* __restrict__ out)
{
    __shared__ __bf16 ldsA[2][4096];   // [buf][kb(2)][seg(4)][row(64)][8]
    __shared__ __bf16 ldsB[2][4096];
    const int t = threadIdx.x;
    const int lane = t & 63, w = t >> 6;
    const int lr = lane & 15, seg = lane >> 4;
    const int rb = blockIdx.x * 64;
    const int n0 = blockIdx.y * 64;

    const __bf16* gAt = comb + (size_t)(rb + (t & 63)) * 512 + ((t >> 6) << 3);
    const __bf16* gBt = woB + (size_t)(n0 + (t & 63)) * 512 + ((t >> 6) << 3);
    __bf16* lA0 = &ldsA[0][t * 8];
    __bf16* lA1 = &ldsA[1][t * 8];
    __bf16* lB0 = &ldsB[0][t * 8];
    __bf16* lB1 = &ldsB[1][t * 8];

    f32x4 acc[4];
#pragma unroll
    for (int ct = 0; ct < 4; ct++) acc[ct] = (f32x4){0.f, 0.f, 0.f, 0.f};

    // prologue: tile 0 (k 0..63) -> buf 0
    gload16(gAt + 0, lA0);
    gload16(gAt + 32, lA0 + 2048);
    gload16(gBt + 0, lB0);
    gload16(gBt + 32, lB0 + 2048);
    __syncthreads();

#pragma unroll 1
    for (int tt = 0; tt < 8; tt++) {
        const int cur = tt & 1;
        if (tt < 7) {
            const int kn = (tt + 1) * 64;
            __bf16* la = cur ? lA0 : lA1;
            __bf16* lb = cur ? lB0 : lB1;
            gload16(gAt + kn, la);
            gload16(gAt + kn + 32, la + 2048);
            gload16(gBt + kn, lb);
            gload16(gBt + kn + 32, lb + 2048);
        }
        const __bf16* cA = ldsA[cur];
        const __bf16* cB = ldsB[cur];
        bf16x8 af[2];
#pragma unroll
        for (int kb = 0; kb < 2; kb++)
            af[kb] = *reinterpret_cast<const bf16x8*>(cA + kb * 2048 + seg * 512 + (w * 16 + lr) * 8);
#pragma unroll
        for (int ct = 0; ct < 4; ct++) {
#pragma unroll
            for (int kb = 0; kb < 2; kb++) {
                bf16x8 bb = *reinterpret_cast<const bf16x8*>(cB + kb * 2048 + seg * 512 + (ct * 16 + lr) * 8);
                acc[ct] = __builtin_amdgcn_mfma_f32_16x16x32_bf16(af[kb], bb, acc[ct], 0, 0, 0);
            }
        }
        __syncthreads();
    }

#pragma unroll
    for (int ct = 0; ct < 4; ct++) {
        int col = n0 + ct * 16 + lr;
        float bo = b_out[col];
#pragma unroll
        for (int r = 0; r < 4; r++) {
            int row = rb + w * 16 + seg * 4 + r;
            size_t idx = (size_t)row * 256 + col;
            float acs = tanhf(acc[ct][r] + bo);
            float ng = (float)comb[(size_t)row * 512 + 256 + col];
            bf16x2 us = *reinterpret_cast<const bf16x2*>(ugsg + idx * 2);
            float ug = (float)us.x, sg = (float)us.y;
            float curr = ng + sg * acs;
            out[idx] = curr + ug * (hidden[idx] - curr);
        }
    }
}

extern "C" void kernel_launch(void* const* d_in, const int* in_sizes, int n_in,
                              void* d_out, int out_size, void* d_ws, size_t ws_size,
                              hipStream_t stream) {
    const float* input_t = (const float*)d_in[0];
    const float* hidden  = (const float*)d_in[1];
    const float* w_ih    = (const float*)d_in[2];
    const float* b_ih    = (const float*)d_in[3];
    const float* w_hh    = (const float*)d_in[4];
    const float* b_hh    = (const float*)d_in[5];
    const float* w_out   = (const float*)d_in[6];
    const float* b_out   = (const float*)d_in[7];
    const float* memory  = (const float*)d_in[8];
    float* out = (float*)d_out;

    __bf16* base  = (__bf16*)d_ws;
    __bf16* wfull = base + E_AB;
    __bf16* woutB = base + E_WF;
    __bf16* comb  = base + E_COMB;
    __bf16* ugsg  = base + E_UGSG;

    cast_kernel<<<320, 256, 0, stream>>>(w_ih, w_hh, w_out, base);
    gates_gemm<<<dim3(128, 8), 256, 0, stream>>>(input_t, hidden, wfull, b_ih, b_hh, comb, ugsg);
    attn_kernel<<<4096, 256, 0, stream>>>(input_t, memory, comb);
    out_gemm<<<dim3(256, 4), 256, 0, stream>>>(comb, woutB, b_out, ugsg, hidden, out);
}

// Round 17
// 191.338 us; speedup vs baseline: 1.0839x; 1.0839x over previous
//
#include <hip/hip_runtime.h>
#include <stdint.h>

#define B_N 16384
#define H_N 256
#define IN_W 258
#define GX_N 70
#define GY_N 70
#define SW_N 2
#define KK_N 25

typedef __bf16 bf16x8 __attribute__((ext_vector_type(8)));
typedef __bf16 bf16x4 __attribute__((ext_vector_type(4)));
typedef __bf16 bf16x2 __attribute__((ext_vector_type(2)));
typedef float f32x4 __attribute__((ext_vector_type(4)));
typedef float f32x2 __attribute__((ext_vector_type(2)));

#define AS1 __attribute__((address_space(1)))
#define AS3 __attribute__((address_space(3)))

static __device__ __forceinline__ void gload16(const void* g, void* l) {
    __builtin_amdgcn_global_load_lds((const AS1 uint32_t*)g, (AS3 uint32_t*)l, 16, 0, 0);
}

// ---- ws layout (bf16 elements) ----
// AB    at 0        : [16384][512]  ([feat|hid])            16 MB
// wfull at 8388608  : [1024][512]   rows j=c*256+col, c in {r,i,s,n};
//                     k<256 -> wih[base_c+col][k], k>=256 -> whh[base_c+col][k-256]
//                     base_c = {0,256,768,512}
// woutB at 8912896  : [256][512]
// comb  at 9043968  : [16384][512]  ([mix|q])               16 MB
// ugsg  at 17432576 : [16384][256][2] (ug,sg interleaved)   16 MB
#define E_AB   8388608ULL
#define E_WF   8912896ULL
#define E_WOUT 9043968ULL
#define E_COMB 9043968ULL
#define E_UGSG 17432576ULL

// 16B-store cast: each thread converts 8 f32 -> bf16x8 per iteration.
// All section boundaries and k-splits are ==0 mod 8.
// NOTE (r16 lesson): do NOT fuse the AB cast into gates — writing AB once
// in bf16 is what keeps gates' A traffic at 16MB and its staging async
// (fusion: gates 45.8->73.2us, FETCH +33MB).
__global__ __launch_bounds__(256) void cast_kernel(
    const float* __restrict__ in_t, const float* __restrict__ hid,
    const float* __restrict__ wih, const float* __restrict__ whh,
    const float* __restrict__ wout, __bf16* __restrict__ dst)
{
    size_t g = (size_t)blockIdx.x * blockDim.x + threadIdx.x;
    size_t stride = (size_t)gridDim.x * blockDim.x;
    for (size_t e = g * 8; e < E_WOUT; e += stride * 8) {
        float s[8];
        if (e < E_AB) {
            size_t row = e >> 9;
            size_t c = e & 511;
            if (c < 256) {
                const f32x2* s2 = reinterpret_cast<const f32x2*>(in_t + row * IN_W + c);
#pragma unroll
                for (int q = 0; q < 4; q++) { f32x2 a = s2[q]; s[q * 2] = a.x; s[q * 2 + 1] = a.y; }
            } else {
                const f32x4* s4 = reinterpret_cast<const f32x4*>(hid + row * 256 + (c - 256));
#pragma unroll
                for (int q = 0; q < 2; q++) { f32x4 a = s4[q]; s[q*4]=a.x; s[q*4+1]=a.y; s[q*4+2]=a.z; s[q*4+3]=a.w; }
            }
        } else if (e < E_WF) {
            size_t off = e - E_AB;
            size_t j = off >> 9;       // 0..1023
            size_t k = off & 511;
            size_t c = j >> 8;         // 0..3
            size_t col = j & 255;
            size_t base = (c == 0) ? 0 : (c == 1) ? 256 : (c == 2) ? 768 : 512;
            const float* srcm = (k < 256) ? wih : whh;
            const f32x4* s4 = reinterpret_cast<const f32x4*>(srcm + (base + col) * 256 + (k & 255));
#pragma unroll
            for (int q = 0; q < 2; q++) { f32x4 a = s4[q]; s[q*4]=a.x; s[q*4+1]=a.y; s[q*4+2]=a.z; s[q*4+3]=a.w; }
        } else {
            const f32x4* s4 = reinterpret_cast<const f32x4*>(wout + (e - E_WF));
#pragma unroll
            for (int q = 0; q < 2; q++) { f32x4 a = s4[q]; s[q*4]=a.x; s[q*4+1]=a.y; s[q*4+2]=a.z; s[q*4+3]=a.w; }
        }
        bf16x8 o;
#pragma unroll
        for (int q = 0; q < 8; q++) o[q] = (__bf16)s[q];
        *reinterpret_cast<bf16x8*>(dst + e) = o;
    }
}

// Fused gates GEMM, K=512 concat form. r6-PROVEN 2-phase dbuf pipeline
// (45.8-48 us, VGPR 64, no spill). Counted-vmcnt grafts regressed twice
// (r3/r7); cast-fusion regressed (r16) — do not retry.
// block = 128 rows x 128 cols (32 hcols x 4 gates), 4 waves, wave 32x128,
// acc 20 f32x4 = 80 regs. LDS 32KB -> 4 blocks/CU (grid 1024 = 4/CU).
__global__ __launch_bounds__(256, 2) void gates_gemm(
    const __bf16* __restrict__ AB, const __bf16* __restrict__ wfull,
    const float* __restrict__ b_ih, const float* __restrict__ b_hh,
    __bf16* __restrict__ comb, __bf16* __restrict__ ugsg)
{
    __shared__ __bf16 ldsA[2][4096];   // [buf][seg(4)][row(128)][8]
    __shared__ __bf16 ldsB[2][4096];   // [buf][seg(4)][brow(128)][8]
    const int t = threadIdx.x;
    const int lane = t & 63, w = t >> 6;
    const int lr = lane & 15, seg = lane >> 4;
    const int rb = blockIdx.x * 128;
    const int h0 = blockIdx.y * 32;

    // staging: thread t owns row (t&127), k-segs {t>>7, (t>>7)+2}
    const int rA = t & 127;
    const int sA = t >> 7;             // 0..1
    const __bf16* gAt = AB + (size_t)(rb + rA) * 512 + sA * 8;
    const int bc = rA >> 5, bcol = rA & 31;  // brow -> wfull row bc*256+h0+bcol
    const __bf16* gBt = wfull + (size_t)(bc * 256 + h0 + bcol) * 512 + sA * 8;
    __bf16* lA0 = &ldsA[0][t * 8];
    __bf16* lA1 = &ldsA[1][t * 8];
    __bf16* lB0 = &ldsB[0][t * 8];
    __bf16* lB1 = &ldsB[1][t * 8];

    f32x4 acc[2][6], accni[2][2], accnh[2][2];
#pragma unroll
    for (int rh = 0; rh < 2; rh++) {
#pragma unroll
        for (int cn = 0; cn < 6; cn++) acc[rh][cn] = (f32x4){0.f, 0.f, 0.f, 0.f};
        accni[rh][0] = (f32x4){0.f, 0.f, 0.f, 0.f};
        accni[rh][1] = (f32x4){0.f, 0.f, 0.f, 0.f};
        accnh[rh][0] = (f32x4){0.f, 0.f, 0.f, 0.f};
        accnh[rh][1] = (f32x4){0.f, 0.f, 0.f, 0.f};
    }

    // prologue: stage tile 0 into buf 0
    gload16(gAt + 0, lA0);
    gload16(gAt + 16, lA0 + 2048);
    gload16(gBt + 0, lB0);
    gload16(gBt + 16, lB0 + 2048);
    __syncthreads();   // implicit vmcnt(0)

#pragma unroll 1
    for (int tt = 0; tt < 16; tt++) {
        const int cur = tt & 1;
        if (tt < 15) {   // issue next tile's stage BEFORE compute
            const int kn = (tt + 1) * 32;
            __bf16* la = cur ? lA0 : lA1;
            __bf16* lb = cur ? lB0 : lB1;
            gload16(gAt + kn, la);
            gload16(gAt + kn + 16, la + 2048);
            gload16(gBt + kn, lb);
            gload16(gBt + kn + 16, lb + 2048);
        }
        const __bf16* cA = ldsA[cur];
        const __bf16* cB = ldsB[cur];
        bf16x8 af[2];
#pragma unroll
        for (int rh = 0; rh < 2; rh++)
            af[rh] = *reinterpret_cast<const bf16x8*>(cA + seg * 1024 + (w * 32 + rh * 16 + lr) * 8);
#pragma unroll
        for (int cn = 0; cn < 6; cn++) {
            const int c = cn >> 1, hh = cn & 1;
            bf16x8 bb = *reinterpret_cast<const bf16x8*>(cB + seg * 1024 + (c * 32 + hh * 16 + lr) * 8);
#pragma unroll
            for (int rh = 0; rh < 2; rh++)
                acc[rh][(c << 1) + hh] = __builtin_amdgcn_mfma_f32_16x16x32_bf16(af[rh], bb, acc[rh][(c << 1) + hh], 0, 0, 0);
        }
        bf16x8 b6 = *reinterpret_cast<const bf16x8*>(cB + seg * 1024 + (96 + lr) * 8);
        bf16x8 b7 = *reinterpret_cast<const bf16x8*>(cB + seg * 1024 + (112 + lr) * 8);
        if (tt < 8) {
#pragma unroll
            for (int rh = 0; rh < 2; rh++) {
                accni[rh][0] = __builtin_amdgcn_mfma_f32_16x16x32_bf16(af[rh], b6, accni[rh][0], 0, 0, 0);
                accni[rh][1] = __builtin_amdgcn_mfma_f32_16x16x32_bf16(af[rh], b7, accni[rh][1], 0, 0, 0);
            }
        } else {
#pragma unroll
            for (int rh = 0; rh < 2; rh++) {
                accnh[rh][0] = __builtin_amdgcn_mfma_f32_16x16x32_bf16(af[rh], b6, accnh[rh][0], 0, 0, 0);
                accnh[rh][1] = __builtin_amdgcn_mfma_f32_16x16x32_bf16(af[rh], b7, accnh[rh][1], 0, 0, 0);
            }
        }
        __syncthreads();   // vmcnt(0): next tile landed; lgkm: reads done
    }

#pragma unroll
    for (int hh = 0; hh < 2; hh++) {
        const int col = h0 + hh * 16 + lr;
        const float br_ = b_ih[col] + b_hh[col];
        const float bi_ = b_ih[col + 256] + b_hh[col + 256];
        const float bs_ = b_ih[col + 768] + b_hh[col + 768];
        const float bni = b_ih[col + 512];
        const float bnh = b_hh[col + 512];
#pragma unroll
        for (int rh = 0; rh < 2; rh++) {
#pragma unroll
            for (int r = 0; r < 4; r++) {
                const int row = rb + w * 32 + rh * 16 + seg * 4 + r;
                float sr = acc[rh][hh][r] + br_;
                float si = acc[rh][2 + hh][r] + bi_;
                float ss = acc[rh][4 + hh][r] + bs_;
                float vni = accni[rh][hh][r] + bni;
                float vnh = accnh[rh][hh][r] + bnh;
                float rg = 1.f / (1.f + __expf(-sr));
                float ug = 1.f / (1.f + __expf(-si));
                float sg = 1.f / (1.f + __expf(-ss));
                float ng = tanhf(vni + rg * vnh);
                comb[(size_t)row * 512 + 256 + col] = (__bf16)ng;
                bf16x2 us;
                us.x = (__bf16)ug;
                us.y = (__bf16)sg;
                *reinterpret_cast<bf16x2*>(ugsg + ((size_t)row * 256 + col) * 2) = us;
            }
        }
    }
}

// DPP 64-lane sum (6 VALU adds, zero DS-pipe ops). CTRL is a template
// param. bound_ctrl=true: invalid source lane reads 0 (sum identity).
template <int CTRL>
static __device__ __forceinline__ float dpp_add_step(float x) {
    int xi = __builtin_bit_cast(int, x);
    int sh = __builtin_amdgcn_update_dpp(0, xi, CTRL, 0xf, 0xf, true);
    return x + __builtin_bit_cast(float, sh);
}
static __device__ __forceinline__ float wave_sum_readlane(float x) {
    x = dpp_add_step<0x111>(x);  // row_shr:1
    x = dpp_add_step<0x112>(x);  // row_shr:2
    x = dpp_add_step<0x114>(x);  // row_shr:4
    x = dpp_add_step<0x118>(x);  // row_shr:8
    x = dpp_add_step<0x142>(x);  // row_bcast:15
    x = dpp_add_step<0x143>(x);  // row_bcast:31 -> lane63 = total
    int s = __builtin_amdgcn_readlane(__builtin_bit_cast(int, x), 63);
    return __builtin_bit_cast(float, s);
}

// Attention v3 (r11-proven, 31.8us): wave per row, coalesced f32x4
// context loads held in registers (v[25], static-indexed), DPP-VALU
// reduction (no DS pipe), redundant per-lane softmax. No LDS.
__global__ __launch_bounds__(256) void attn_kernel(
    const float* __restrict__ in_t, const float* __restrict__ memory,
    __bf16* __restrict__ comb)
{
    const int w = threadIdx.x >> 6;
    const int lane = threadIdx.x & 63;
    const int b = blockIdx.x * 4 + w;
    const float* row_in = in_t + (size_t)b * IN_W;
    int gx = (int)row_in[256] + SW_N;
    int gy = (int)row_in[257] + SW_N;
    gx = min(max(gx, 0), GX_N - 1);
    gy = min(max(gy, 0), GY_N - 1);

    int xs[5], ys[5];
#pragma unroll
    for (int d = 0; d < 5; d++) {
        xs[d] = min(max(gx + d - SW_N, 0), GX_N - 1);
        ys[d] = min(max(gy + d - SW_N, 0), GY_N - 1);
    }

    bf16x4 qb = *reinterpret_cast<const bf16x4*>(comb + (size_t)b * 512 + 256 + lane * 4);
    const float q0 = (float)qb.x, q1 = (float)qb.y, q2 = (float)qb.z, q3 = (float)qb.w;

    f32x4 v[KK_N];
    float sc[KK_N];
#pragma unroll
    for (int k = 0; k < KK_N; k++) {       // full unroll: v[],sc[] static-indexed
        const int i = k / 5, j = k % 5;    // compile-time
        const f32x4* cp = reinterpret_cast<const f32x4*>(
            memory + ((size_t)xs[i] * GY_N + ys[j]) * H_N);
        v[k] = cp[lane];                   // coalesced 1KB/wave
        float p = q0 * v[k].x + q1 * v[k].y + q2 * v[k].z + q3 * v[k].w;
        sc[k] = wave_sum_readlane(p);      // 6 VALU-DPP + readlane, no DS
    }

    // softmax over 25 uniform scores (ref: attn==0 -> -inf mask; all-masked -> 0)
#pragma unroll
    for (int k = 0; k < KK_N; k++) sc[k] = (sc[k] == 0.f) ? -INFINITY : sc[k];
    float mx = -INFINITY;
#pragma unroll
    for (int k = 0; k < KK_N; k++) mx = fmaxf(mx, sc[k]);
    float d = 0.f;
    if (mx > -INFINITY) {
#pragma unroll
        for (int k = 0; k < KK_N; k++) { sc[k] = __expf(sc[k] - mx); d += sc[k]; }
    } else {
#pragma unroll
        for (int k = 0; k < KK_N; k++) sc[k] = 0.f;
    }
    const float inv = (d != 0.f) ? 1.f / d : 0.f;

    f32x4 o = (f32x4){0.f, 0.f, 0.f, 0.f};
#pragma unroll
    for (int k = 0; k < KK_N; k++) {
        const float wk = sc[k] * inv;
        o.x += wk * v[k].x; o.y += wk * v[k].y; o.z += wk * v[k].z; o.w += wk * v[k].w;
    }
    bf16x4 ob;
    ob.x = (__bf16)o.x; ob.y = (__bf16)o.y; ob.z = (__bf16)o.z; ob.w = (__bf16)o.w;
    *reinterpret_cast<bf16x4*>(comb + (size_t)b * 512 + lane * 4) = ob;
}

// Output GEMM (K=512) + tanh + final blend. r15 BK=64 version (8 K-steps,
// proven -3us): tile 64x64, 2-phase dbuf, LDS [buf][kb(2)][seg(4)][row(64)][8]
// = 32KB -> 4 blocks/CU at (256,4).
__global__ __launch_bounds__(256, 4) void out_gemm(
    const __bf16* __restrict__ comb, const __bf16* __restrict__ woB,
    const float* __restrict__ b_out, const __bf16* __restrict__ ugsg,
    const float* __restrict__ hidden, float* __restrict__ out)
{
    __shared__ __bf16 ldsA[2][4096];   // [buf][kb(2)][seg(4)][row(64)][8]
    __shared__ __bf16 ldsB[2][4096];
    const int t = threadIdx.x;
    const int lane = t & 63, w = t >> 6;
    const int lr = lane & 15, seg = lane >> 4;
    const int rb = blockIdx.x * 64;
    const int n0 = blockIdx.y * 64;

    const __bf16* gAt = comb + (size_t)(rb + (t & 63)) * 512 + ((t >> 6) << 3);
    const __bf16* gBt = woB + (size_t)(n0 + (t & 63)) * 512 + ((t >> 6) << 3);
    __bf16* lA0 = &ldsA[0][t * 8];
    __bf16* lA1 = &ldsA[1][t * 8];
    __bf16* lB0 = &ldsB[0][t * 8];
    __bf16* lB1 = &ldsB[1][t * 8];

    f32x4 acc[4];
#pragma unroll
    for (int ct = 0; ct < 4; ct++) acc[ct] = (f32x4){0.f, 0.f, 0.f, 0.f};

    // prologue: tile 0 (k 0..63) -> buf 0
    gload16(gAt + 0, lA0);
    gload16(gAt + 32, lA0 + 2048);
    gload16(gBt + 0, lB0);
    gload16(gBt + 32, lB0 + 2048);
    __syncthreads();

#pragma unroll 1
    for (int tt = 0; tt < 8; tt++) {
        const int cur = tt & 1;
        if (tt < 7) {
            const int kn = (tt + 1) * 64;
            __bf16* la = cur ? lA0 : lA1;
            __bf16* lb = cur ? lB0 : lB1;
            gload16(gAt + kn, la);
            gload16(gAt + kn + 32, la + 2048);
            gload16(gBt + kn, lb);
            gload16(gBt + kn + 32, lb + 2048);
        }
        const __bf16* cA = ldsA[cur];
        const __bf16* cB = ldsB[cur];
        bf16x8 af[2];
#pragma unroll
        for (int kb = 0; kb < 2; kb++)
            af[kb] = *reinterpret_cast<const bf16x8*>(cA + kb * 2048 + seg * 512 + (w * 16 + lr) * 8);
#pragma unroll
        for (int ct = 0; ct < 4; ct++) {
#pragma unroll
            for (int kb = 0; kb < 2; kb++) {
                bf16x8 bb = *reinterpret_cast<const bf16x8*>(cB + kb * 2048 + seg * 512 + (ct * 16 + lr) * 8);
                acc[ct] = __builtin_amdgcn_mfma_f32_16x16x32_bf16(af[kb], bb, acc[ct], 0, 0, 0);
            }
        }
        __syncthreads();
    }

#pragma unroll
    for (int ct = 0; ct < 4; ct++) {
        int col = n0 + ct * 16 + lr;
        float bo = b_out[col];
#pragma unroll
        for (int r = 0; r < 4; r++) {
            int row = rb + w * 16 + seg * 4 + r;
            size_t idx = (size_t)row * 256 + col;
            float acs = tanhf(acc[ct][r] + bo);
            float ng = (float)comb[(size_t)row * 512 + 256 + col];
            bf16x2 us = *reinterpret_cast<const bf16x2*>(ugsg + idx * 2);
            float ug = (float)us.x, sg = (float)us.y;
            float curr = ng + sg * acs;
            out[idx] = curr + ug * (hidden[idx] - curr);
        }
    }
}

extern "C" void kernel_launch(void* const* d_in, const int* in_sizes, int n_in,
                              void* d_out, int out_size, void* d_ws, size_t ws_size,
                              hipStream_t stream) {
    const float* input_t = (const float*)d_in[0];
    const float* hidden  = (const float*)d_in[1];
    const float* w_ih    = (const float*)d_in[2];
    const float* b_ih    = (const float*)d_in[3];
    const float* w_hh    = (const float*)d_in[4];
    const float* b_hh    = (const float*)d_in[5];
    const float* w_out   = (const float*)d_in[6];
    const float* b_out   = (const float*)d_in[7];
    const float* memory  = (const float*)d_in[8];
    float* out = (float*)d_out;

    __bf16* base  = (__bf16*)d_ws;
    __bf16* AB    = base;
    __bf16* wfull = base + E_AB;
    __bf16* woutB = base + E_WF;
    __bf16* comb  = base + E_COMB;
    __bf16* ugsg  = base + E_UGSG;

    cast_kernel<<<4096, 256, 0, stream>>>(input_t, hidden, w_ih, w_hh, w_out, base);
    gates_gemm<<<dim3(128, 8), 256, 0, stream>>>(AB, wfull, b_ih, b_hh, comb, ugsg);
    attn_kernel<<<4096, 256, 0, stream>>>(input_t, memory, comb);
    out_gemm<<<dim3(256, 4), 256, 0, stream>>>(comb, woutB, b_out, ugsg, hidden, out);
}